// Round 19
// baseline (96.556 us; speedup 1.0000x reference)
//
#include <hip/hip_runtime.h>
#include <math.h>

constexpr int NB = 8, NS = 2048, ND = 65;
constexpr int KX = 64;      // packed x stride (d 0..63); d=64 separate fp32
constexpr int LP = 68;      // LDS row stride for QK tiles: 136B rows -> 2-way-free banks
constexpr int VD = 80;      // padded d rows for V^T
constexpr size_t OUTSZ = (size_t)NB * NS * ND;
constexpr size_t CONVN = (size_t)NB * NS * KX;   // packed x elems per array
constexpr size_t VTN   = (size_t)NB * VD * NS;   // V^T elems (hi only)

typedef short short8 __attribute__((ext_vector_type(8)));
typedef float f32x4 __attribute__((ext_vector_type(4)));

union S8U { short8 v; ushort4 h[2]; };
__device__ __forceinline__ short8 ld8(const ushort* p) {   // 8B-aligned LDS read
    S8U u; u.h[0] = *(const ushort4*)p; u.h[1] = *(const ushort4*)(p + 4); return u.v;
}

__device__ __forceinline__ ushort f2bf(float f) {
    uint u = __float_as_uint(f);
    return (ushort)((u + 0x7fffu + ((u >> 16) & 1u)) >> 16);   // RNE
}
__device__ __forceinline__ float bf2f(ushort h) {
    return __uint_as_float((uint)h << 16);
}

// ---------------------------------------------------------------------------
// k0_prep (merged k0x + k0v): blocks [0,512) convert x -> (hi,lo,x64);
// blocks [512,1024) transpose V -> V^T bf16 [b, d(80 zero-pad), t].
// ---------------------------------------------------------------------------
__global__ __launch_bounds__(256)
void k0_prep(const float* __restrict__ x, ushort* __restrict__ xhi,
             ushort* __restrict__ xlo, float* __restrict__ x64,
             const float* __restrict__ v, ushort* __restrict__ vthi)
{
    const int bid = blockIdx.x;
    const int tid = threadIdx.x;
    if (bid < 512) {
        int i = bid * 256 + tid;
        int row = i >> 3, g = i & 7;
        int d0 = g * 8;
        short8 vh, vl;
        #pragma unroll
        for (int e = 0; e < 8; ++e) {
            float val = x[(size_t)row * ND + d0 + e];
            ushort h = f2bf(val);
            vh[e] = (short)h;
            vl[e] = (short)f2bf(val - bf2f(h));
        }
        *(short8*)&xhi[(size_t)row * KX + d0] = vh;
        *(short8*)&xlo[(size_t)row * KX + d0] = vl;
        if (g == 0) x64[row] = x[(size_t)row * ND + 64];
    } else {
        __shared__ float sT[32][66];
        const int b2 = bid - 512;
        const int b = b2 >> 6, t0 = (b2 & 63) * 32;
        const float* vb = v + (size_t)b * NS * ND;
        for (int i = tid; i < 32 * ND; i += 256) {
            int t = i / ND, d = i - t * ND;
            sT[t][d] = vb[(size_t)(t0 + t) * ND + d];
        }
        __syncthreads();
        for (int i = tid; i < VD * 32; i += 256) {
            int d = i >> 5, t = i & 31;
            float val = (d < ND) ? sT[t][d] : 0.0f;
            vthi[((size_t)b * VD + d) * NS + t0 + t] = f2bf(val);
        }
    }
}

// ---------------------------------------------------------------------------
// k1u: per (batch, 64-row block, COLUMN-HALF), grid 512 (2 blocks/CU).
// T14 B-staging (issue-early/write-late reg prefetch). Swapped MFMA
// (lane&15 = S-row, regs = 4 consecutive S-cols -> ushort4 E stores);
// d=64 fp32 FMA; E = z - sqrt(z^2-1) u16; rowsum partials -> ws.
// ---------------------------------------------------------------------------
__global__ __launch_bounds__(512, 4)
void k1u_scores(const ushort* __restrict__ xhi, const ushort* __restrict__ xlo,
                const float* __restrict__ x64, const float* __restrict__ tptr,
                ushort* __restrict__ eg, float* __restrict__ rsp)
{
    __shared__ __align__(16) ushort sAh[64 * LP], sAl[64 * LP];   // 8704 B each
    __shared__ __align__(16) ushort sBh[128 * LP], sBl[128 * LP]; // 17408 B each
    __shared__ __align__(16) float sB64[128];

    const int tid = threadIdx.x;
    // XCD swizzle: dispatch d -> logical f = (d%8)*64 + d/8 (bijective, 512%8==0)
    const int f  = (blockIdx.x & 7) * 64 + (blockIdx.x >> 3);
    const int b  = f >> 6;
    const int rblk = (f >> 1) & 31;
    const int ch = f & 1;               // column half
    const int r0 = rblk * 64;
    const int tc0 = ch * (NS / 2);
    const int lane = tid & 63;
    const int q = lane >> 4, c = lane & 15;
    const int w  = tid >> 6;
    const int wr = w >> 2;          // 0..1  (32-row slab)
    const int wc = w & 3;           // 0..3  (32-col slab)
    const float invT = 1.0f / (tptr[0] + 1e-8f);
    const bool fastT = (invT == 1.0f);

    const ushort* xhb = xhi + (size_t)b * NS * KX;
    const ushort* xlb = xlo + (size_t)b * NS * KX;
    const float*  x64b = x64 + (size_t)b * NS;
    ushort* erow = eg + ((size_t)b * NS + r0) * NS;

    // T14 prefetch registers for the B tile (2 staging iters x hi/lo)
    uint4 pbh[2], pbl[2];
    float pb64;
    auto loadB = [&](int tc) {
        #pragma unroll
        for (int r = 0; r < 2; ++r) {
            int i = tid + r * 512;
            int row = i >> 3, g = i & 7;
            pbh[r] = *(const uint4*)&xhb[(size_t)(tc + row) * KX + g * 8];
            pbl[r] = *(const uint4*)&xlb[(size_t)(tc + row) * KX + g * 8];
        }
        if (tid < 128) pb64 = x64b[tc + tid];
    };

    loadB(tc0);   // prologue: chunk 0 in flight while A stages

    // stage A rows once (64 x 64, hi+lo) into stride-68 tiles
    for (int i = tid; i < 64 * 8; i += 512) {
        int row = i >> 3, g = i & 7;
        uint4 vh = *(const uint4*)&xhb[(size_t)(r0 + row) * KX + g * 8];
        uint4 vl = *(const uint4*)&xlb[(size_t)(r0 + row) * KX + g * 8];
        int so = row * LP + g * 8;
        *(uint2*)&sAh[so]     = make_uint2(vh.x, vh.y);
        *(uint2*)&sAh[so + 4] = make_uint2(vh.z, vh.w);
        *(uint2*)&sAl[so]     = make_uint2(vl.x, vl.y);
        *(uint2*)&sAl[so + 4] = make_uint2(vl.z, vl.w);
    }
    __syncthreads();
    if (tid < 64) { sAh[tid * LP] ^= 0x8000; sAl[tid * LP] ^= 0x8000; }  // negate time dim

    // per-lane fp32 d64 A value: this lane's S-row is c (within each rf tile)
    float a64r[2];
    #pragma unroll
    for (int rf = 0; rf < 2; ++rf)
        a64r[rf] = x64b[r0 + wr * 32 + rf * 16 + c];

    float rsum[2] = {0.0f, 0.0f};

    for (int tcl = 0; tcl < NS / 2; tcl += 128) {
        const int tc = tc0 + tcl;
        __syncthreads();    // previous chunk's frag reads done
        // write-late: publish prefetched B tile
        #pragma unroll
        for (int r = 0; r < 2; ++r) {
            int i = tid + r * 512;
            int row = i >> 3, g = i & 7;
            int so = row * LP + g * 8;
            *(uint2*)&sBh[so]     = make_uint2(pbh[r].x, pbh[r].y);
            *(uint2*)&sBh[so + 4] = make_uint2(pbh[r].z, pbh[r].w);
            *(uint2*)&sBl[so]     = make_uint2(pbl[r].x, pbl[r].y);
            *(uint2*)&sBl[so + 4] = make_uint2(pbl[r].z, pbl[r].w);
        }
        if (tid < 128) sB64[tid] = pb64;
        __syncthreads();

        // issue-early: next chunk's loads drain during MFMA+epilogue
        if (tcl + 128 < NS / 2) loadB(tc + 128);

        f32x4 acc[2][2];
        #pragma unroll
        for (int rf = 0; rf < 2; ++rf)
            #pragma unroll
            for (int cf = 0; cf < 2; ++cf)
                #pragma unroll
                for (int j = 0; j < 4; ++j) acc[rf][cf][j] = 0.0f;

        #pragma unroll
        for (int kc = 0; kc < 2; ++kc) {
            const int koff = kc * 32 + q * 8;
            short8 ah[2], al[2], bh[2], bl[2];
            #pragma unroll
            for (int rf = 0; rf < 2; ++rf) {
                int ro = (wr * 32 + rf * 16 + c) * LP + koff;
                ah[rf] = ld8(&sAh[ro]);
                al[rf] = ld8(&sAl[ro]);
            }
            #pragma unroll
            for (int cf = 0; cf < 2; ++cf) {
                int co = (wc * 32 + cf * 16 + c) * LP + koff;
                bh[cf] = ld8(&sBh[co]);
                bl[cf] = ld8(&sBl[co]);
            }
            // swapped operands: D = S^T tile -> lane&15 = S-row, regs = 4 S-cols
            #pragma unroll
            for (int rf = 0; rf < 2; ++rf)
                #pragma unroll
                for (int cf = 0; cf < 2; ++cf) {
                    acc[rf][cf] = __builtin_amdgcn_mfma_f32_16x16x32_bf16(bh[cf], ah[rf], acc[rf][cf], 0, 0, 0);
                    acc[rf][cf] = __builtin_amdgcn_mfma_f32_16x16x32_bf16(bl[cf], ah[rf], acc[rf][cf], 0, 0, 0);
                    acc[rf][cf] = __builtin_amdgcn_mfma_f32_16x16x32_bf16(bh[cf], al[rf], acc[rf][cf], 0, 0, 0);
                }
        }

        // epilogue: + fp32 d64 term, acosh->e (rcp-free), packed ushort4 store
        #pragma unroll
        for (int rf = 0; rf < 2; ++rf) {
            const int row = wr * 32 + rf * 16 + c;
            #pragma unroll
            for (int cf = 0; cf < 2; ++cf) {
                float4 b64v = *(const float4*)&sB64[wc * 32 + cf * 16 + q * 4];
                float e4[4];
                #pragma unroll
                for (int j = 0; j < 4; ++j) {
                    float bj = (j == 0) ? b64v.x : (j == 1) ? b64v.y
                             : (j == 2) ? b64v.z : b64v.w;
                    float accf = acc[rf][cf][j] + a64r[rf] * bj;
                    float z = -accf;
                    z = fminf(fmaxf(z, 1.0000001f), 50.0f);
                    float s = __fsqrt_rn(z * z - 1.0f);
                    float e = fastT ? (z - s)                   // == 1/(z+s)
                                    : __expf(-__logf(z + s) * invT);
                    e4[j] = e;
                    rsum[rf] += e;
                }
                ushort4 pk = make_ushort4(
                    (ushort)__float2uint_rn(e4[0] * 65535.0f),
                    (ushort)__float2uint_rn(e4[1] * 65535.0f),
                    (ushort)__float2uint_rn(e4[2] * 65535.0f),
                    (ushort)__float2uint_rn(e4[3] * 65535.0f));
                *(ushort4*)&erow[(size_t)row * NS + tc + wc * 32 + cf * 16 + q * 4] = pk;
            }
        }
    }

    __syncthreads();                    // all frag reads done -> sBh reusable
    float* sSum = (float*)sBh;          // [4][64] aliases dead B tile
    #pragma unroll
    for (int rf = 0; rf < 2; ++rf) {
        float v = rsum[rf];
        v += __shfl_xor(v, 16, 64);     // sum the 4 q-lanes sharing this row
        v += __shfl_xor(v, 32, 64);
        if (q == 0) sSum[wc * 64 + wr * 32 + rf * 16 + c] = v;
    }
    __syncthreads();
    if (tid < 64)
        rsp[(size_t)ch * NB * NS + (size_t)b * NS + r0 + tid] =
            sSum[tid] + sSum[64 + tid] + sSum[128 + tid] + sSum[192 + tid];
}

// ---------------------------------------------------------------------------
// k2u: per (batch, 32-row block), 512 threads = 8 waves (4 k-slices x
// 2 row-halves). inv computed in-block from the two rowsum halves.
// T14-prefetched u16 E + V^T regs; phase 1 = unpack*inv -> NONTEMPORAL
// f32x4 attn store (attn never re-read on device -> keep eg/vthi resident
// in L2/L3) + P bf16 hi/lo split to LDS + V^T ds_write; PV MFMA; NT out.
// ---------------------------------------------------------------------------
__global__ __launch_bounds__(512, 4)
void k2u_pv(const ushort* __restrict__ eg, const ushort* __restrict__ vthi,
            const float* __restrict__ rsp, float* __restrict__ attn,
            float* __restrict__ out)
{
    __shared__ __align__(16) char smem[40960];
    ushort* sAh = (ushort*)smem;                  // 32*136 u16 [0, 8704)
    ushort* sAl = sAh + 32 * 136;                 // [8704, 17408)
    ushort* sVh = sAl + 32 * 136;                 // 80*136 [17408, 39168)
    float*  sInvL = (float*)(smem + 39168);       // 128 B [39168, 39296)
    float*  sRed = (float*)smem;                  // 40960 B, post-loop only

    const int tid = threadIdx.x;
    // XCD swizzle: dispatch d -> logical f = (d%8)*64 + d/8 (bijective, 512%8==0)
    const int f  = (blockIdx.x & 7) * 64 + (blockIdx.x >> 3);
    const int b  = f >> 6;
    const int r0 = (f & 63) * 32;
    const int lane = tid & 63;
    const int q = lane >> 4, c = lane & 15;
    const int w = tid >> 6;
    const int wk = w & 3;             // k-slice 0..3 within each 128-chunk
    const int rfh = w >> 2;           // row half 0..1 (16 rows each)

    if (tid < 32) {
        size_t i = (size_t)b * NS + r0 + tid;
        sInvL[tid] = (1.0f / (rsp[i] + rsp[(size_t)NB * NS + i])) * (1.0f / 65535.0f);
    }

    const ushort* erow = eg + ((size_t)b * NS + r0) * NS;
    float* arow = attn + ((size_t)b * NS + r0) * NS;
    const ushort* vh = vthi + (size_t)b * VD * NS;

    short8 ereg;                      // 512 thr = 32 rows x 16 groups: 1 each
    short8 vregh[3];
    auto loadE = [&](int kt) {
        int row = tid >> 4, c8 = tid & 15;
        ereg = *(const short8*)&erow[(size_t)row * NS + kt + c8 * 8];
    };
    auto loadV = [&](int kt) {
        #pragma unroll
        for (int rep = 0; rep < 3; ++rep) {
            int i = tid + rep * 512;
            if (i < VD * 16) {
                int d = i >> 4, c8 = i & 15;
                vregh[rep] = *(const short8*)&vh[(size_t)d * NS + kt + c8 * 8];
            }
        }
    };

    f32x4 acc[5];
    #pragma unroll
    for (int ff = 0; ff < 5; ++ff)
        #pragma unroll
        for (int j = 0; j < 4; ++j) acc[ff][j] = 0.0f;

    loadE(0);
    loadV(0);
    __syncthreads();

    for (int kt = 0; kt < NS; kt += 128) {
        // phase 1: unpack u16 -> en, NT f32x4 attn store, bf16 split to sA
        {
            int row = tid >> 4, c8 = tid & 15;
            float inv2 = sInvL[row];
            float en[8];
            #pragma unroll
            for (int i = 0; i < 8; ++i)
                en[i] = (float)(ushort)ereg[i] * inv2;
            f32x4 fa = {en[0], en[1], en[2], en[3]};
            f32x4 fb = {en[4], en[5], en[6], en[7]};
            __builtin_nontemporal_store(fa, (f32x4*)&arow[(size_t)row * NS + kt + c8 * 8]);
            __builtin_nontemporal_store(fb, (f32x4*)&arow[(size_t)row * NS + kt + c8 * 8 + 4]);
            ushort h[8], l[8];
            #pragma unroll
            for (int i = 0; i < 8; ++i) {
                h[i] = f2bf(en[i]);
                l[i] = f2bf(en[i] - bf2f(h[i]));
            }
            int so = row * 136 + c8 * 8;
            *(ushort4*)&sAh[so]     = make_ushort4(h[0], h[1], h[2], h[3]);
            *(ushort4*)&sAh[so + 4] = make_ushort4(h[4], h[5], h[6], h[7]);
            *(ushort4*)&sAl[so]     = make_ushort4(l[0], l[1], l[2], l[3]);
            *(ushort4*)&sAl[so + 4] = make_ushort4(l[4], l[5], l[6], l[7]);
        }
        #pragma unroll
        for (int rep = 0; rep < 3; ++rep) {
            int i = tid + rep * 512;
            if (i < VD * 16) {
                int d = i >> 4, c8 = i & 15;
                *(short8*)&sVh[d * 136 + c8 * 8] = vregh[rep];
            }
        }
        __syncthreads();

        if (kt + 128 < NS) { loadE(kt + 128); loadV(kt + 128); }

        const int koff = wk * 32 + q * 8;
        short8 ah = *(const short8*)&sAh[(rfh * 16 + c) * 136 + koff];
        short8 al = *(const short8*)&sAl[(rfh * 16 + c) * 136 + koff];
        #pragma unroll
        for (int ff = 0; ff < 5; ++ff) {
            short8 bh = *(const short8*)&sVh[(ff * 16 + c) * 136 + koff];
            acc[ff] = __builtin_amdgcn_mfma_f32_16x16x32_bf16(ah, bh, acc[ff], 0, 0, 0);
            acc[ff] = __builtin_amdgcn_mfma_f32_16x16x32_bf16(al, bh, acc[ff], 0, 0, 0);
        }
        __syncthreads();
    }

    // k-slice partials -> sRed (aliases staging), reduce over wk, write out
    #pragma unroll
    for (int ff = 0; ff < 5; ++ff)
        #pragma unroll
        for (int j = 0; j < 4; ++j) {
            int r = rfh * 16 + q * 4 + j;
            int d = ff * 16 + c;
            sRed[((size_t)wk * 32 + r) * 80 + d] = acc[ff][j];
        }
    __syncthreads();
    for (int i = tid; i < 32 * 80; i += 512) {
        int r = i / 80, d = i - r * 80;
        float s = sRed[i] + sRed[2560 + i] + sRed[5120 + i] + sRed[7680 + i];
        if (d < ND)
            __builtin_nontemporal_store(s, &out[((size_t)b * NS + r0 + r) * ND + d]);
    }
}

extern "C" void kernel_launch(void* const* d_in, const int* in_sizes, int n_in,
                              void* d_out, int out_size, void* d_ws, size_t ws_size,
                              hipStream_t stream) {
    const float* x      = (const float*)d_in[0];
    const float* values = (const float*)d_in[1];
    const float* temp   = (const float*)d_in[2];

    float* out  = (float*)d_out;
    float* attn = out + OUTSZ;

    // ws: xhi/xlo 4.19MB + vthi 2.62MB + x64/rsp 0.33MB + eg 67.1MB ~ 74.3MB
    ushort* xhi  = (ushort*)d_ws;
    ushort* xlo  = xhi + CONVN;
    ushort* vthi = xlo + CONVN;
    float*  x64  = (float*)(vthi + VTN);
    float*  rsp  = x64 + (size_t)NB * NS;           // 2 * NB*NS partial sums
    ushort* eg   = (ushort*)(rsp + 2 * (size_t)NB * NS);

    k0_prep<<<1024, 256, 0, stream>>>(x, xhi, xlo, x64, values, vthi);
    k1u_scores<<<512, 512, 0, stream>>>(xhi, xlo, x64, temp, eg, rsp);
    k2u_pv<<<512, 512, 0, stream>>>(eg, vthi, rsp, attn, out);
}

// Round 20
// 78.529 us; speedup vs baseline: 1.2296x; 1.2296x over previous
//
#include <hip/hip_runtime.h>
#include <math.h>

constexpr int NB = 8, NS = 2048, ND = 65;
constexpr int KX = 64;      // packed x stride (d 0..63); d=64 separate fp32
constexpr int LP = 68;      // LDS row stride for QK tiles: 136B rows -> 2-way-free banks
constexpr int VD = 80;      // padded d rows for V^T
constexpr size_t OUTSZ = (size_t)NB * NS * ND;
constexpr size_t CONVN = (size_t)NB * NS * KX;   // packed x elems per array
constexpr size_t VTN   = (size_t)NB * VD * NS;   // V^T elems (hi only)

typedef short short8 __attribute__((ext_vector_type(8)));
typedef float f32x4 __attribute__((ext_vector_type(4)));

union S8U { short8 v; ushort4 h[2]; };
__device__ __forceinline__ short8 ld8(const ushort* p) {   // 8B-aligned LDS read
    S8U u; u.h[0] = *(const ushort4*)p; u.h[1] = *(const ushort4*)(p + 4); return u.v;
}

__device__ __forceinline__ ushort f2bf(float f) {
    uint u = __float_as_uint(f);
    return (ushort)((u + 0x7fffu + ((u >> 16) & 1u)) >> 16);   // RNE
}
__device__ __forceinline__ float bf2f(ushort h) {
    return __uint_as_float((uint)h << 16);
}

// ---------------------------------------------------------------------------
// k0_prep (merged k0x + k0v): blocks [0,512) convert x -> (hi,lo,x64);
// blocks [512,1024) transpose V -> V^T bf16 [b, d(80 zero-pad), t].
// ---------------------------------------------------------------------------
__global__ __launch_bounds__(256)
void k0_prep(const float* __restrict__ x, ushort* __restrict__ xhi,
             ushort* __restrict__ xlo, float* __restrict__ x64,
             const float* __restrict__ v, ushort* __restrict__ vthi)
{
    const int bid = blockIdx.x;
    const int tid = threadIdx.x;
    if (bid < 512) {
        int i = bid * 256 + tid;
        int row = i >> 3, g = i & 7;
        int d0 = g * 8;
        short8 vh, vl;
        #pragma unroll
        for (int e = 0; e < 8; ++e) {
            float val = x[(size_t)row * ND + d0 + e];
            ushort h = f2bf(val);
            vh[e] = (short)h;
            vl[e] = (short)f2bf(val - bf2f(h));
        }
        *(short8*)&xhi[(size_t)row * KX + d0] = vh;
        *(short8*)&xlo[(size_t)row * KX + d0] = vl;
        if (g == 0) x64[row] = x[(size_t)row * ND + 64];
    } else {
        __shared__ float sT[32][66];
        const int b2 = bid - 512;
        const int b = b2 >> 6, t0 = (b2 & 63) * 32;
        const float* vb = v + (size_t)b * NS * ND;
        for (int i = tid; i < 32 * ND; i += 256) {
            int t = i / ND, d = i - t * ND;
            sT[t][d] = vb[(size_t)(t0 + t) * ND + d];
        }
        __syncthreads();
        for (int i = tid; i < VD * 32; i += 256) {
            int d = i >> 5, t = i & 31;
            float val = (d < ND) ? sT[t][d] : 0.0f;
            vthi[((size_t)b * VD + d) * NS + t0 + t] = f2bf(val);
        }
    }
}

// ---------------------------------------------------------------------------
// k1u: per (batch, 64-row block, COLUMN-HALF), grid 512 (2 blocks/CU).
// T14 B-staging (issue-early/write-late reg prefetch). Swapped MFMA
// (lane&15 = S-row, regs = 4 consecutive S-cols -> ushort4 E stores);
// d=64 fp32 FMA; E = z - sqrt(z^2-1) u16; rowsum partials -> ws.
// ---------------------------------------------------------------------------
__global__ __launch_bounds__(512, 4)
void k1u_scores(const ushort* __restrict__ xhi, const ushort* __restrict__ xlo,
                const float* __restrict__ x64, const float* __restrict__ tptr,
                ushort* __restrict__ eg, float* __restrict__ rsp)
{
    __shared__ __align__(16) ushort sAh[64 * LP], sAl[64 * LP];   // 8704 B each
    __shared__ __align__(16) ushort sBh[128 * LP], sBl[128 * LP]; // 17408 B each
    __shared__ __align__(16) float sB64[128];

    const int tid = threadIdx.x;
    // XCD swizzle: dispatch d -> logical f = (d%8)*64 + d/8 (bijective, 512%8==0)
    const int f  = (blockIdx.x & 7) * 64 + (blockIdx.x >> 3);
    const int b  = f >> 6;
    const int rblk = (f >> 1) & 31;
    const int ch = f & 1;               // column half
    const int r0 = rblk * 64;
    const int tc0 = ch * (NS / 2);
    const int lane = tid & 63;
    const int q = lane >> 4, c = lane & 15;
    const int w  = tid >> 6;
    const int wr = w >> 2;          // 0..1  (32-row slab)
    const int wc = w & 3;           // 0..3  (32-col slab)
    const float invT = 1.0f / (tptr[0] + 1e-8f);
    const bool fastT = (invT == 1.0f);

    const ushort* xhb = xhi + (size_t)b * NS * KX;
    const ushort* xlb = xlo + (size_t)b * NS * KX;
    const float*  x64b = x64 + (size_t)b * NS;
    ushort* erow = eg + ((size_t)b * NS + r0) * NS;

    // T14 prefetch registers for the B tile (2 staging iters x hi/lo)
    uint4 pbh[2], pbl[2];
    float pb64;
    auto loadB = [&](int tc) {
        #pragma unroll
        for (int r = 0; r < 2; ++r) {
            int i = tid + r * 512;
            int row = i >> 3, g = i & 7;
            pbh[r] = *(const uint4*)&xhb[(size_t)(tc + row) * KX + g * 8];
            pbl[r] = *(const uint4*)&xlb[(size_t)(tc + row) * KX + g * 8];
        }
        if (tid < 128) pb64 = x64b[tc + tid];
    };

    loadB(tc0);   // prologue: chunk 0 in flight while A stages

    // stage A rows once (64 x 64, hi+lo) into stride-68 tiles
    for (int i = tid; i < 64 * 8; i += 512) {
        int row = i >> 3, g = i & 7;
        uint4 vh = *(const uint4*)&xhb[(size_t)(r0 + row) * KX + g * 8];
        uint4 vl = *(const uint4*)&xlb[(size_t)(r0 + row) * KX + g * 8];
        int so = row * LP + g * 8;
        *(uint2*)&sAh[so]     = make_uint2(vh.x, vh.y);
        *(uint2*)&sAh[so + 4] = make_uint2(vh.z, vh.w);
        *(uint2*)&sAl[so]     = make_uint2(vl.x, vl.y);
        *(uint2*)&sAl[so + 4] = make_uint2(vl.z, vl.w);
    }
    __syncthreads();
    if (tid < 64) { sAh[tid * LP] ^= 0x8000; sAl[tid * LP] ^= 0x8000; }  // negate time dim

    // per-lane fp32 d64 A value: this lane's S-row is c (within each rf tile)
    float a64r[2];
    #pragma unroll
    for (int rf = 0; rf < 2; ++rf)
        a64r[rf] = x64b[r0 + wr * 32 + rf * 16 + c];

    float rsum[2] = {0.0f, 0.0f};

    for (int tcl = 0; tcl < NS / 2; tcl += 128) {
        const int tc = tc0 + tcl;
        __syncthreads();    // previous chunk's frag reads done
        // write-late: publish prefetched B tile
        #pragma unroll
        for (int r = 0; r < 2; ++r) {
            int i = tid + r * 512;
            int row = i >> 3, g = i & 7;
            int so = row * LP + g * 8;
            *(uint2*)&sBh[so]     = make_uint2(pbh[r].x, pbh[r].y);
            *(uint2*)&sBh[so + 4] = make_uint2(pbh[r].z, pbh[r].w);
            *(uint2*)&sBl[so]     = make_uint2(pbl[r].x, pbl[r].y);
            *(uint2*)&sBl[so + 4] = make_uint2(pbl[r].z, pbl[r].w);
        }
        if (tid < 128) sB64[tid] = pb64;
        __syncthreads();

        // issue-early: next chunk's loads drain during MFMA+epilogue
        if (tcl + 128 < NS / 2) loadB(tc + 128);

        f32x4 acc[2][2];
        #pragma unroll
        for (int rf = 0; rf < 2; ++rf)
            #pragma unroll
            for (int cf = 0; cf < 2; ++cf)
                #pragma unroll
                for (int j = 0; j < 4; ++j) acc[rf][cf][j] = 0.0f;

        #pragma unroll
        for (int kc = 0; kc < 2; ++kc) {
            const int koff = kc * 32 + q * 8;
            short8 ah[2], al[2], bh[2], bl[2];
            #pragma unroll
            for (int rf = 0; rf < 2; ++rf) {
                int ro = (wr * 32 + rf * 16 + c) * LP + koff;
                ah[rf] = ld8(&sAh[ro]);
                al[rf] = ld8(&sAl[ro]);
            }
            #pragma unroll
            for (int cf = 0; cf < 2; ++cf) {
                int co = (wc * 32 + cf * 16 + c) * LP + koff;
                bh[cf] = ld8(&sBh[co]);
                bl[cf] = ld8(&sBl[co]);
            }
            // swapped operands: D = S^T tile -> lane&15 = S-row, regs = 4 S-cols
            #pragma unroll
            for (int rf = 0; rf < 2; ++rf)
                #pragma unroll
                for (int cf = 0; cf < 2; ++cf) {
                    acc[rf][cf] = __builtin_amdgcn_mfma_f32_16x16x32_bf16(bh[cf], ah[rf], acc[rf][cf], 0, 0, 0);
                    acc[rf][cf] = __builtin_amdgcn_mfma_f32_16x16x32_bf16(bl[cf], ah[rf], acc[rf][cf], 0, 0, 0);
                    acc[rf][cf] = __builtin_amdgcn_mfma_f32_16x16x32_bf16(bh[cf], al[rf], acc[rf][cf], 0, 0, 0);
                }
        }

        // epilogue: + fp32 d64 term, acosh->e (rcp-free), packed ushort4 store
        #pragma unroll
        for (int rf = 0; rf < 2; ++rf) {
            const int row = wr * 32 + rf * 16 + c;
            #pragma unroll
            for (int cf = 0; cf < 2; ++cf) {
                float4 b64v = *(const float4*)&sB64[wc * 32 + cf * 16 + q * 4];
                float e4[4];
                #pragma unroll
                for (int j = 0; j < 4; ++j) {
                    float bj = (j == 0) ? b64v.x : (j == 1) ? b64v.y
                             : (j == 2) ? b64v.z : b64v.w;
                    float accf = acc[rf][cf][j] + a64r[rf] * bj;
                    float z = -accf;
                    z = fminf(fmaxf(z, 1.0000001f), 50.0f);
                    float s = __fsqrt_rn(z * z - 1.0f);
                    float e = fastT ? (z - s)                   // == 1/(z+s)
                                    : __expf(-__logf(z + s) * invT);
                    e4[j] = e;
                    rsum[rf] += e;
                }
                ushort4 pk = make_ushort4(
                    (ushort)__float2uint_rn(e4[0] * 65535.0f),
                    (ushort)__float2uint_rn(e4[1] * 65535.0f),
                    (ushort)__float2uint_rn(e4[2] * 65535.0f),
                    (ushort)__float2uint_rn(e4[3] * 65535.0f));
                *(ushort4*)&erow[(size_t)row * NS + tc + wc * 32 + cf * 16 + q * 4] = pk;
            }
        }
    }

    __syncthreads();                    // all frag reads done -> sBh reusable
    float* sSum = (float*)sBh;          // [4][64] aliases dead B tile
    #pragma unroll
    for (int rf = 0; rf < 2; ++rf) {
        float v = rsum[rf];
        v += __shfl_xor(v, 16, 64);     // sum the 4 q-lanes sharing this row
        v += __shfl_xor(v, 32, 64);
        if (q == 0) sSum[wc * 64 + wr * 32 + rf * 16 + c] = v;
    }
    __syncthreads();
    if (tid < 64)
        rsp[(size_t)ch * NB * NS + (size_t)b * NS + r0 + tid] =
            sSum[tid] + sSum[64 + tid] + sSum[128 + tid] + sSum[192 + tid];
}

// ---------------------------------------------------------------------------
// k2u: per (batch, 32-row block), 512 threads = 8 waves (4 k-slices x
// 2 row-halves). inv computed in-block from the two rowsum halves.
// T14-prefetched u16 E + V^T regs; phase 1 = unpack*inv -> f32x4 attn store
// (regular stores — NT stores measured 17us SLOWER for this stream, r19)
// + P bf16 hi/lo split to LDS + V^T ds_write; PV = 2-product MFMA.
// ---------------------------------------------------------------------------
__global__ __launch_bounds__(512, 4)
void k2u_pv(const ushort* __restrict__ eg, const ushort* __restrict__ vthi,
            const float* __restrict__ rsp, float* __restrict__ attn,
            float* __restrict__ out)
{
    __shared__ __align__(16) char smem[40960];
    ushort* sAh = (ushort*)smem;                  // 32*136 u16 [0, 8704)
    ushort* sAl = sAh + 32 * 136;                 // [8704, 17408)
    ushort* sVh = sAl + 32 * 136;                 // 80*136 [17408, 39168)
    float*  sInvL = (float*)(smem + 39168);       // 128 B [39168, 39296)
    float*  sRed = (float*)smem;                  // 40960 B, post-loop only

    const int tid = threadIdx.x;
    // XCD swizzle: dispatch d -> logical f = (d%8)*64 + d/8 (bijective, 512%8==0)
    const int f  = (blockIdx.x & 7) * 64 + (blockIdx.x >> 3);
    const int b  = f >> 6;
    const int r0 = (f & 63) * 32;
    const int lane = tid & 63;
    const int q = lane >> 4, c = lane & 15;
    const int w = tid >> 6;
    const int wk = w & 3;             // k-slice 0..3 within each 128-chunk
    const int rfh = w >> 2;           // row half 0..1 (16 rows each)

    if (tid < 32) {
        size_t i = (size_t)b * NS + r0 + tid;
        sInvL[tid] = (1.0f / (rsp[i] + rsp[(size_t)NB * NS + i])) * (1.0f / 65535.0f);
    }

    const ushort* erow = eg + ((size_t)b * NS + r0) * NS;
    float* arow = attn + ((size_t)b * NS + r0) * NS;
    const ushort* vh = vthi + (size_t)b * VD * NS;

    short8 ereg;                      // 512 thr = 32 rows x 16 groups: 1 each
    short8 vregh[3];
    auto loadE = [&](int kt) {
        int row = tid >> 4, c8 = tid & 15;
        ereg = *(const short8*)&erow[(size_t)row * NS + kt + c8 * 8];
    };
    auto loadV = [&](int kt) {
        #pragma unroll
        for (int rep = 0; rep < 3; ++rep) {
            int i = tid + rep * 512;
            if (i < VD * 16) {
                int d = i >> 4, c8 = i & 15;
                vregh[rep] = *(const short8*)&vh[(size_t)d * NS + kt + c8 * 8];
            }
        }
    };

    f32x4 acc[5];
    #pragma unroll
    for (int ff = 0; ff < 5; ++ff)
        #pragma unroll
        for (int j = 0; j < 4; ++j) acc[ff][j] = 0.0f;

    loadE(0);
    loadV(0);
    __syncthreads();

    for (int kt = 0; kt < NS; kt += 128) {
        // phase 1: unpack u16 -> en, f32x4 attn store, bf16 split to sA
        {
            int row = tid >> 4, c8 = tid & 15;
            float inv2 = sInvL[row];
            float en[8];
            #pragma unroll
            for (int i = 0; i < 8; ++i)
                en[i] = (float)(ushort)ereg[i] * inv2;
            float4 fa = {en[0], en[1], en[2], en[3]};
            float4 fb = {en[4], en[5], en[6], en[7]};
            *(float4*)&arow[(size_t)row * NS + kt + c8 * 8]     = fa;
            *(float4*)&arow[(size_t)row * NS + kt + c8 * 8 + 4] = fb;
            ushort h[8], l[8];
            #pragma unroll
            for (int i = 0; i < 8; ++i) {
                h[i] = f2bf(en[i]);
                l[i] = f2bf(en[i] - bf2f(h[i]));
            }
            int so = row * 136 + c8 * 8;
            *(ushort4*)&sAh[so]     = make_ushort4(h[0], h[1], h[2], h[3]);
            *(ushort4*)&sAh[so + 4] = make_ushort4(h[4], h[5], h[6], h[7]);
            *(ushort4*)&sAl[so]     = make_ushort4(l[0], l[1], l[2], l[3]);
            *(ushort4*)&sAl[so + 4] = make_ushort4(l[4], l[5], l[6], l[7]);
        }
        #pragma unroll
        for (int rep = 0; rep < 3; ++rep) {
            int i = tid + rep * 512;
            if (i < VD * 16) {
                int d = i >> 4, c8 = i & 15;
                *(short8*)&sVh[d * 136 + c8 * 8] = vregh[rep];
            }
        }
        __syncthreads();

        if (kt + 128 < NS) { loadE(kt + 128); loadV(kt + 128); }

        const int koff = wk * 32 + q * 8;
        short8 ah = *(const short8*)&sAh[(rfh * 16 + c) * 136 + koff];
        short8 al = *(const short8*)&sAl[(rfh * 16 + c) * 136 + koff];
        #pragma unroll
        for (int ff = 0; ff < 5; ++ff) {
            short8 bh = *(const short8*)&sVh[(ff * 16 + c) * 136 + koff];
            acc[ff] = __builtin_amdgcn_mfma_f32_16x16x32_bf16(ah, bh, acc[ff], 0, 0, 0);
            acc[ff] = __builtin_amdgcn_mfma_f32_16x16x32_bf16(al, bh, acc[ff], 0, 0, 0);
        }
        __syncthreads();
    }

    // k-slice partials -> sRed (aliases staging), reduce over wk, write out
    #pragma unroll
    for (int ff = 0; ff < 5; ++ff)
        #pragma unroll
        for (int j = 0; j < 4; ++j) {
            int r = rfh * 16 + q * 4 + j;
            int d = ff * 16 + c;
            sRed[((size_t)wk * 32 + r) * 80 + d] = acc[ff][j];
        }
    __syncthreads();
    for (int i = tid; i < 32 * 80; i += 512) {
        int r = i / 80, d = i - r * 80;
        float s = sRed[i] + sRed[2560 + i] + sRed[5120 + i] + sRed[7680 + i];
        if (d < ND) out[((size_t)b * NS + r0 + r) * ND + d] = s;
    }
}

extern "C" void kernel_launch(void* const* d_in, const int* in_sizes, int n_in,
                              void* d_out, int out_size, void* d_ws, size_t ws_size,
                              hipStream_t stream) {
    const float* x      = (const float*)d_in[0];
    const float* values = (const float*)d_in[1];
    const float* temp   = (const float*)d_in[2];

    float* out  = (float*)d_out;
    float* attn = out + OUTSZ;

    // ws: xhi/xlo 4.19MB + vthi 2.62MB + x64/rsp 0.33MB + eg 67.1MB ~ 74.3MB
    ushort* xhi  = (ushort*)d_ws;
    ushort* xlo  = xhi + CONVN;
    ushort* vthi = xlo + CONVN;
    float*  x64  = (float*)(vthi + VTN);
    float*  rsp  = x64 + (size_t)NB * NS;           // 2 * NB*NS partial sums
    ushort* eg   = (ushort*)(rsp + 2 * (size_t)NB * NS);

    k0_prep<<<1024, 256, 0, stream>>>(x, xhi, xlo, x64, values, vthi);
    k1u_scores<<<512, 512, 0, stream>>>(xhi, xlo, x64, temp, eg, rsp);
    k2u_pv<<<512, 512, 0, stream>>>(eg, vthi, rsp, attn, out);
}

// Round 21
// 77.991 us; speedup vs baseline: 1.2380x; 1.0069x over previous
//
#include <hip/hip_runtime.h>
#include <math.h>

constexpr int NB = 8, NS = 2048, ND = 65;
constexpr int KX = 64;      // packed x stride (d 0..63); d=64 separate fp32
constexpr int LP = 68;      // LDS row stride for QK tiles: 136B rows -> 2-way-free banks
constexpr int VD = 80;      // padded d rows for V^T
constexpr size_t OUTSZ = (size_t)NB * NS * ND;
constexpr size_t CONVN = (size_t)NB * NS * KX;   // packed x elems per array
constexpr size_t VTN   = (size_t)NB * VD * NS;   // V^T elems (hi only)

typedef short short8 __attribute__((ext_vector_type(8)));
typedef float f32x4 __attribute__((ext_vector_type(4)));

union S8U { short8 v; ushort4 h[2]; };
__device__ __forceinline__ short8 ld8(const ushort* p) {   // 8B-aligned LDS read
    S8U u; u.h[0] = *(const ushort4*)p; u.h[1] = *(const ushort4*)(p + 4); return u.v;
}

__device__ __forceinline__ ushort f2bf(float f) {
    uint u = __float_as_uint(f);
    return (ushort)((u + 0x7fffu + ((u >> 16) & 1u)) >> 16);   // RNE
}
__device__ __forceinline__ float bf2f(ushort h) {
    return __uint_as_float((uint)h << 16);
}

// ---------------------------------------------------------------------------
// k0_prep (merged k0x + k0v): blocks [0,512) convert x -> (hi,lo,x64);
// blocks [512,1024) transpose V -> V^T bf16 [b, d(80 zero-pad), t].
// ---------------------------------------------------------------------------
__global__ __launch_bounds__(256)
void k0_prep(const float* __restrict__ x, ushort* __restrict__ xhi,
             ushort* __restrict__ xlo, float* __restrict__ x64,
             const float* __restrict__ v, ushort* __restrict__ vthi)
{
    const int bid = blockIdx.x;
    const int tid = threadIdx.x;
    if (bid < 512) {
        int i = bid * 256 + tid;
        int row = i >> 3, g = i & 7;
        int d0 = g * 8;
        short8 vh, vl;
        #pragma unroll
        for (int e = 0; e < 8; ++e) {
            float val = x[(size_t)row * ND + d0 + e];
            ushort h = f2bf(val);
            vh[e] = (short)h;
            vl[e] = (short)f2bf(val - bf2f(h));
        }
        *(short8*)&xhi[(size_t)row * KX + d0] = vh;
        *(short8*)&xlo[(size_t)row * KX + d0] = vl;
        if (g == 0) x64[row] = x[(size_t)row * ND + 64];
    } else {
        __shared__ float sT[32][66];
        const int b2 = bid - 512;
        const int b = b2 >> 6, t0 = (b2 & 63) * 32;
        const float* vb = v + (size_t)b * NS * ND;
        for (int i = tid; i < 32 * ND; i += 256) {
            int t = i / ND, d = i - t * ND;
            sT[t][d] = vb[(size_t)(t0 + t) * ND + d];
        }
        __syncthreads();
        for (int i = tid; i < VD * 32; i += 256) {
            int d = i >> 5, t = i & 31;
            float val = (d < ND) ? sT[t][d] : 0.0f;
            vthi[((size_t)b * VD + d) * NS + t0 + t] = f2bf(val);
        }
    }
}

// ---------------------------------------------------------------------------
// k1u: per (batch, 64-row block, COLUMN-QUARTER), grid 1024 -> 3 blocks/CU
// resident (LDS 52.7KB x 3 = 158KB), 24 waves/CU. Column split does NOT
// duplicate B staging (1024 blocks x 4 chunks = r20's 512 x 8); only the
// cheap A-stage duplicates (L2-hot). T14 B reg-prefetch. Swapped MFMA
// (lane&15 = S-row, regs = 4 consecutive S-cols -> ushort4 E stores);
// d=64 fp32 FMA; E = z - sqrt(z^2-1) u16; rowsum partials (x4) -> ws.
// ---------------------------------------------------------------------------
__global__ __launch_bounds__(512, 4)
void k1u_scores(const ushort* __restrict__ xhi, const ushort* __restrict__ xlo,
                const float* __restrict__ x64, const float* __restrict__ tptr,
                ushort* __restrict__ eg, float* __restrict__ rsp)
{
    __shared__ __align__(16) ushort sAh[64 * LP], sAl[64 * LP];   // 8704 B each
    __shared__ __align__(16) ushort sBh[128 * LP], sBl[128 * LP]; // 17408 B each
    __shared__ __align__(16) float sB64[128];

    const int tid = threadIdx.x;
    // XCD swizzle: dispatch d -> logical f = (d%8)*128 + d/8 (bijective, 1024%8==0)
    const int f  = (blockIdx.x & 7) * 128 + (blockIdx.x >> 3);
    const int b  = f >> 7;
    const int rblk = (f >> 2) & 31;
    const int ch = f & 3;               // column quarter
    const int r0 = rblk * 64;
    const int tc0 = ch * (NS / 4);
    const int lane = tid & 63;
    const int q = lane >> 4, c = lane & 15;
    const int w  = tid >> 6;
    const int wr = w >> 2;          // 0..1  (32-row slab)
    const int wc = w & 3;           // 0..3  (32-col slab)
    const float invT = 1.0f / (tptr[0] + 1e-8f);
    const bool fastT = (invT == 1.0f);

    const ushort* xhb = xhi + (size_t)b * NS * KX;
    const ushort* xlb = xlo + (size_t)b * NS * KX;
    const float*  x64b = x64 + (size_t)b * NS;
    ushort* erow = eg + ((size_t)b * NS + r0) * NS;

    // T14 prefetch registers for the B tile (2 staging iters x hi/lo)
    uint4 pbh[2], pbl[2];
    float pb64;
    auto loadB = [&](int tc) {
        #pragma unroll
        for (int r = 0; r < 2; ++r) {
            int i = tid + r * 512;
            int row = i >> 3, g = i & 7;
            pbh[r] = *(const uint4*)&xhb[(size_t)(tc + row) * KX + g * 8];
            pbl[r] = *(const uint4*)&xlb[(size_t)(tc + row) * KX + g * 8];
        }
        if (tid < 128) pb64 = x64b[tc + tid];
    };

    loadB(tc0);   // prologue: chunk 0 in flight while A stages

    // stage A rows once (64 x 64, hi+lo) into stride-68 tiles
    for (int i = tid; i < 64 * 8; i += 512) {
        int row = i >> 3, g = i & 7;
        uint4 vh = *(const uint4*)&xhb[(size_t)(r0 + row) * KX + g * 8];
        uint4 vl = *(const uint4*)&xlb[(size_t)(r0 + row) * KX + g * 8];
        int so = row * LP + g * 8;
        *(uint2*)&sAh[so]     = make_uint2(vh.x, vh.y);
        *(uint2*)&sAh[so + 4] = make_uint2(vh.z, vh.w);
        *(uint2*)&sAl[so]     = make_uint2(vl.x, vl.y);
        *(uint2*)&sAl[so + 4] = make_uint2(vl.z, vl.w);
    }
    __syncthreads();
    if (tid < 64) { sAh[tid * LP] ^= 0x8000; sAl[tid * LP] ^= 0x8000; }  // negate time dim

    // per-lane fp32 d64 A value: this lane's S-row is c (within each rf tile)
    float a64r[2];
    #pragma unroll
    for (int rf = 0; rf < 2; ++rf)
        a64r[rf] = x64b[r0 + wr * 32 + rf * 16 + c];

    float rsum[2] = {0.0f, 0.0f};

    for (int tcl = 0; tcl < NS / 4; tcl += 128) {
        const int tc = tc0 + tcl;
        __syncthreads();    // previous chunk's frag reads done
        // write-late: publish prefetched B tile
        #pragma unroll
        for (int r = 0; r < 2; ++r) {
            int i = tid + r * 512;
            int row = i >> 3, g = i & 7;
            int so = row * LP + g * 8;
            *(uint2*)&sBh[so]     = make_uint2(pbh[r].x, pbh[r].y);
            *(uint2*)&sBh[so + 4] = make_uint2(pbh[r].z, pbh[r].w);
            *(uint2*)&sBl[so]     = make_uint2(pbl[r].x, pbl[r].y);
            *(uint2*)&sBl[so + 4] = make_uint2(pbl[r].z, pbl[r].w);
        }
        if (tid < 128) sB64[tid] = pb64;
        __syncthreads();

        // issue-early: next chunk's loads drain during MFMA+epilogue
        if (tcl + 128 < NS / 4) loadB(tc + 128);

        f32x4 acc[2][2];
        #pragma unroll
        for (int rf = 0; rf < 2; ++rf)
            #pragma unroll
            for (int cf = 0; cf < 2; ++cf)
                #pragma unroll
                for (int j = 0; j < 4; ++j) acc[rf][cf][j] = 0.0f;

        #pragma unroll
        for (int kc = 0; kc < 2; ++kc) {
            const int koff = kc * 32 + q * 8;
            short8 ah[2], al[2], bh[2], bl[2];
            #pragma unroll
            for (int rf = 0; rf < 2; ++rf) {
                int ro = (wr * 32 + rf * 16 + c) * LP + koff;
                ah[rf] = ld8(&sAh[ro]);
                al[rf] = ld8(&sAl[ro]);
            }
            #pragma unroll
            for (int cf = 0; cf < 2; ++cf) {
                int co = (wc * 32 + cf * 16 + c) * LP + koff;
                bh[cf] = ld8(&sBh[co]);
                bl[cf] = ld8(&sBl[co]);
            }
            // swapped operands: D = S^T tile -> lane&15 = S-row, regs = 4 S-cols
            #pragma unroll
            for (int rf = 0; rf < 2; ++rf)
                #pragma unroll
                for (int cf = 0; cf < 2; ++cf) {
                    acc[rf][cf] = __builtin_amdgcn_mfma_f32_16x16x32_bf16(bh[cf], ah[rf], acc[rf][cf], 0, 0, 0);
                    acc[rf][cf] = __builtin_amdgcn_mfma_f32_16x16x32_bf16(bl[cf], ah[rf], acc[rf][cf], 0, 0, 0);
                    acc[rf][cf] = __builtin_amdgcn_mfma_f32_16x16x32_bf16(bh[cf], al[rf], acc[rf][cf], 0, 0, 0);
                }
        }

        // epilogue: + fp32 d64 term, acosh->e (rcp-free), packed ushort4 store
        #pragma unroll
        for (int rf = 0; rf < 2; ++rf) {
            const int row = wr * 32 + rf * 16 + c;
            #pragma unroll
            for (int cf = 0; cf < 2; ++cf) {
                float4 b64v = *(const float4*)&sB64[wc * 32 + cf * 16 + q * 4];
                float e4[4];
                #pragma unroll
                for (int j = 0; j < 4; ++j) {
                    float bj = (j == 0) ? b64v.x : (j == 1) ? b64v.y
                             : (j == 2) ? b64v.z : b64v.w;
                    float accf = acc[rf][cf][j] + a64r[rf] * bj;
                    float z = -accf;
                    z = fminf(fmaxf(z, 1.0000001f), 50.0f);
                    float s = __fsqrt_rn(z * z - 1.0f);
                    float e = fastT ? (z - s)                   // == 1/(z+s)
                                    : __expf(-__logf(z + s) * invT);
                    e4[j] = e;
                    rsum[rf] += e;
                }
                ushort4 pk = make_ushort4(
                    (ushort)__float2uint_rn(e4[0] * 65535.0f),
                    (ushort)__float2uint_rn(e4[1] * 65535.0f),
                    (ushort)__float2uint_rn(e4[2] * 65535.0f),
                    (ushort)__float2uint_rn(e4[3] * 65535.0f));
                *(ushort4*)&erow[(size_t)row * NS + tc + wc * 32 + cf * 16 + q * 4] = pk;
            }
        }
    }

    __syncthreads();                    // all frag reads done -> sBh reusable
    float* sSum = (float*)sBh;          // [4][64] aliases dead B tile
    #pragma unroll
    for (int rf = 0; rf < 2; ++rf) {
        float v = rsum[rf];
        v += __shfl_xor(v, 16, 64);     // sum the 4 q-lanes sharing this row
        v += __shfl_xor(v, 32, 64);
        if (q == 0) sSum[wc * 64 + wr * 32 + rf * 16 + c] = v;
    }
    __syncthreads();
    if (tid < 64)
        rsp[(size_t)ch * NB * NS + (size_t)b * NS + r0 + tid] =
            sSum[tid] + sSum[64 + tid] + sSum[128 + tid] + sSum[192 + tid];
}

// ---------------------------------------------------------------------------
// k2u: per (batch, 32-row block), 512 threads = 8 waves (4 k-slices x
// 2 row-halves). inv computed in-block from the FOUR rowsum quarters.
// T14-prefetched u16 E + V^T regs; phase 1 = unpack*inv -> f32x4 attn store
// (regular stores — NT stores measured 17us SLOWER for this stream, r19)
// + P bf16 hi/lo split to LDS + V^T ds_write; PV = 2-product MFMA.
// ---------------------------------------------------------------------------
__global__ __launch_bounds__(512, 4)
void k2u_pv(const ushort* __restrict__ eg, const ushort* __restrict__ vthi,
            const float* __restrict__ rsp, float* __restrict__ attn,
            float* __restrict__ out)
{
    __shared__ __align__(16) char smem[40960];
    ushort* sAh = (ushort*)smem;                  // 32*136 u16 [0, 8704)
    ushort* sAl = sAh + 32 * 136;                 // [8704, 17408)
    ushort* sVh = sAl + 32 * 136;                 // 80*136 [17408, 39168)
    float*  sInvL = (float*)(smem + 39168);       // 128 B [39168, 39296)
    float*  sRed = (float*)smem;                  // 40960 B, post-loop only

    const int tid = threadIdx.x;
    // XCD swizzle: dispatch d -> logical f = (d%8)*64 + d/8 (bijective, 512%8==0)
    const int f  = (blockIdx.x & 7) * 64 + (blockIdx.x >> 3);
    const int b  = f >> 6;
    const int r0 = (f & 63) * 32;
    const int lane = tid & 63;
    const int q = lane >> 4, c = lane & 15;
    const int w = tid >> 6;
    const int wk = w & 3;             // k-slice 0..3 within each 128-chunk
    const int rfh = w >> 2;           // row half 0..1 (16 rows each)

    if (tid < 32) {
        size_t i = (size_t)b * NS + r0 + tid;
        const size_t P = (size_t)NB * NS;
        sInvL[tid] = (1.0f / (rsp[i] + rsp[P + i] + rsp[2 * P + i] + rsp[3 * P + i]))
                   * (1.0f / 65535.0f);
    }

    const ushort* erow = eg + ((size_t)b * NS + r0) * NS;
    float* arow = attn + ((size_t)b * NS + r0) * NS;
    const ushort* vh = vthi + (size_t)b * VD * NS;

    short8 ereg;                      // 512 thr = 32 rows x 16 groups: 1 each
    short8 vregh[3];
    auto loadE = [&](int kt) {
        int row = tid >> 4, c8 = tid & 15;
        ereg = *(const short8*)&erow[(size_t)row * NS + kt + c8 * 8];
    };
    auto loadV = [&](int kt) {
        #pragma unroll
        for (int rep = 0; rep < 3; ++rep) {
            int i = tid + rep * 512;
            if (i < VD * 16) {
                int d = i >> 4, c8 = i & 15;
                vregh[rep] = *(const short8*)&vh[(size_t)d * NS + kt + c8 * 8];
            }
        }
    };

    f32x4 acc[5];
    #pragma unroll
    for (int ff = 0; ff < 5; ++ff)
        #pragma unroll
        for (int j = 0; j < 4; ++j) acc[ff][j] = 0.0f;

    loadE(0);
    loadV(0);
    __syncthreads();

    for (int kt = 0; kt < NS; kt += 128) {
        // phase 1: unpack u16 -> en, f32x4 attn store, bf16 split to sA
        {
            int row = tid >> 4, c8 = tid & 15;
            float inv2 = sInvL[row];
            float en[8];
            #pragma unroll
            for (int i = 0; i < 8; ++i)
                en[i] = (float)(ushort)ereg[i] * inv2;
            float4 fa = {en[0], en[1], en[2], en[3]};
            float4 fb = {en[4], en[5], en[6], en[7]};
            *(float4*)&arow[(size_t)row * NS + kt + c8 * 8]     = fa;
            *(float4*)&arow[(size_t)row * NS + kt + c8 * 8 + 4] = fb;
            ushort h[8], l[8];
            #pragma unroll
            for (int i = 0; i < 8; ++i) {
                h[i] = f2bf(en[i]);
                l[i] = f2bf(en[i] - bf2f(h[i]));
            }
            int so = row * 136 + c8 * 8;
            *(ushort4*)&sAh[so]     = make_ushort4(h[0], h[1], h[2], h[3]);
            *(ushort4*)&sAh[so + 4] = make_ushort4(h[4], h[5], h[6], h[7]);
            *(ushort4*)&sAl[so]     = make_ushort4(l[0], l[1], l[2], l[3]);
            *(ushort4*)&sAl[so + 4] = make_ushort4(l[4], l[5], l[6], l[7]);
        }
        #pragma unroll
        for (int rep = 0; rep < 3; ++rep) {
            int i = tid + rep * 512;
            if (i < VD * 16) {
                int d = i >> 4, c8 = i & 15;
                *(short8*)&sVh[d * 136 + c8 * 8] = vregh[rep];
            }
        }
        __syncthreads();

        if (kt + 128 < NS) { loadE(kt + 128); loadV(kt + 128); }

        const int koff = wk * 32 + q * 8;
        short8 ah = *(const short8*)&sAh[(rfh * 16 + c) * 136 + koff];
        short8 al = *(const short8*)&sAl[(rfh * 16 + c) * 136 + koff];
        #pragma unroll
        for (int ff = 0; ff < 5; ++ff) {
            short8 bh = *(const short8*)&sVh[(ff * 16 + c) * 136 + koff];
            acc[ff] = __builtin_amdgcn_mfma_f32_16x16x32_bf16(ah, bh, acc[ff], 0, 0, 0);
            acc[ff] = __builtin_amdgcn_mfma_f32_16x16x32_bf16(al, bh, acc[ff], 0, 0, 0);
        }
        __syncthreads();
    }

    // k-slice partials -> sRed (aliases staging), reduce over wk, write out
    #pragma unroll
    for (int ff = 0; ff < 5; ++ff)
        #pragma unroll
        for (int j = 0; j < 4; ++j) {
            int r = rfh * 16 + q * 4 + j;
            int d = ff * 16 + c;
            sRed[((size_t)wk * 32 + r) * 80 + d] = acc[ff][j];
        }
    __syncthreads();
    for (int i = tid; i < 32 * 80; i += 512) {
        int r = i / 80, d = i - r * 80;
        float s = sRed[i] + sRed[2560 + i] + sRed[5120 + i] + sRed[7680 + i];
        if (d < ND) out[((size_t)b * NS + r0 + r) * ND + d] = s;
    }
}

extern "C" void kernel_launch(void* const* d_in, const int* in_sizes, int n_in,
                              void* d_out, int out_size, void* d_ws, size_t ws_size,
                              hipStream_t stream) {
    const float* x      = (const float*)d_in[0];
    const float* values = (const float*)d_in[1];
    const float* temp   = (const float*)d_in[2];

    float* out  = (float*)d_out;
    float* attn = out + OUTSZ;

    // ws: xhi/xlo 4.19MB + vthi 2.62MB + x64/rsp 0.39MB + eg 67.1MB ~ 74.4MB
    ushort* xhi  = (ushort*)d_ws;
    ushort* xlo  = xhi + CONVN;
    ushort* vthi = xlo + CONVN;
    float*  x64  = (float*)(vthi + VTN);
    float*  rsp  = x64 + (size_t)NB * NS;           // 4 * NB*NS partial sums
    ushort* eg   = (ushort*)(rsp + 4 * (size_t)NB * NS);

    k0_prep<<<1024, 256, 0, stream>>>(x, xhi, xlo, x64, values, vthi);
    k1u_scores<<<1024, 512, 0, stream>>>(xhi, xlo, x64, temp, eg, rsp);
    k2u_pv<<<512, 512, 0, stream>>>(eg, vthi, rsp, attn, out);
}